// Round 8
// baseline (76.395 us; speedup 1.0000x reference)
//
#include <hip/hip_runtime.h>
#include <math.h>

#define NFEAT  512
#define NHID   128
#define NCLASS 70
#define NIDX   10000
#define NTILE  625            // 625 blocks x 16 rows

typedef float  f32x4  __attribute__((ext_vector_type(4)));
typedef __bf16 bf16x8 __attribute__((ext_vector_type(8)));

static __device__ __forceinline__ unsigned short f2bf(float f) {
    unsigned u = __builtin_bit_cast(unsigned, f);
    u += 0x7fffu + ((u >> 16) & 1u);
    return (unsigned short)(u >> 16);
}
static __device__ __forceinline__ float bf2f(unsigned short h) {
    unsigned u = ((unsigned)h) << 16;
    return __builtin_bit_cast(float, u);
}
static __device__ __forceinline__ bf16x8 pack8(float4 a, float4 b) {
    bf16x8 r;
    r[0] = (__bf16)a.x; r[1] = (__bf16)a.y; r[2] = (__bf16)a.z; r[3] = (__bf16)a.w;
    r[4] = (__bf16)b.x; r[5] = (__bf16)b.y; r[6] = (__bf16)b.z; r[7] = (__bf16)b.w;
    return r;
}
static __device__ __forceinline__ bf16x8 pack8s(float4 a, float4 b, float s) {
    bf16x8 r;
    r[0] = (__bf16)(a.x * s); r[1] = (__bf16)(a.y * s); r[2] = (__bf16)(a.z * s); r[3] = (__bf16)(a.w * s);
    r[4] = (__bf16)(b.x * s); r[5] = (__bf16)(b.y * s); r[6] = (__bf16)(b.z * s); r[7] = (__bf16)(b.w * s);
    return r;
}
static __device__ __forceinline__ f32x4 MFMA(bf16x8 a, bf16x8 b, f32x4 c) {
    return __builtin_amdgcn_mfma_f32_16x16x32_bf16(a, b, c, 0, 0, 0);
}
static __device__ __forceinline__ bf16x8 ldsAx(const unsigned short* base, int row, int colb, int rstride) {
    return *(const bf16x8*)((const char*)base + row * rstride + (colb ^ ((row & 7) << 4)));
}
static __device__ __forceinline__ void ldsW1(unsigned short* base, int row, int col, unsigned short v) {
    *(unsigned short*)((char*)base + row * 256 + ((col * 2) ^ ((row & 7) << 4))) = v;
}
static __device__ __forceinline__ float ldsR1(const unsigned short* base, int row, int col) {
    return bf2f(*(const unsigned short*)((const char*)base + row * 256 + ((col * 2) ^ ((row & 7) << 4))));
}

// Single self-contained kernel: gather + normalize + 4 MFMA stages + softmax.
// Weights consumed directly as f32 (L2-resident), converted to bf16 fragments
// in-register with depth-1 prefetch in every K loop. No workspace, one node.
__global__ __launch_bounds__(512) void hyper_one(
    const float* __restrict__ x, const float* __restrict__ sf,
    const int* __restrict__ idx,
    const float* __restrict__ W0, const float* __restrict__ W1,
    const float* __restrict__ G1, const float* __restrict__ G2,
    const float* __restrict__ GT, const float* __restrict__ Wc,
    float* __restrict__ out)
{
    __shared__ __align__(16) unsigned short Xbuf[2][16][NFEAT]; // 32 KB swizzled bf16
    __shared__ __align__(16) unsigned short Hbuf[2][16][NHID];  // 8 KB
    __shared__ float scl2[16];

    unsigned short* G12 = &Xbuf[0][0][0];                  // [2][16][128] (X dead after B)
    unsigned short* FIX = &Xbuf[0][0][0] + 4096;           // [16][128]
    float*          LOG = (float*)(&Xbuf[0][0][0] + 6144); // [16][80]

    const int tid  = threadIdx.x;
    const int bid  = blockIdx.x;
    const int w    = tid >> 6;          // wave 0..7
    const int lane = tid & 63;
    const int ln   = lane & 15, lg = lane >> 4;
    const int tB = w >> 2, nq = w & 3;
    const f32x4 zero4 = {0.f, 0.f, 0.f, 0.f};

    // ---- gather: wave w owns rows p = 4w..4w+3 (p = t*16+m); issue volley first ----
    float4 gv[8];
    {
        const float* srcs[4];
        #pragma unroll
        for (int j = 0; j < 4; ++j) {
            int p = w * 4 + j, t = p >> 4, m = p & 15;
            srcs[j] = (t ? sf : x) + (size_t)idx[bid * 16 + m] * NFEAT + lane * 8;
        }
        #pragma unroll
        for (int j = 0; j < 4; ++j) {
            gv[2 * j]     = ((const float4*)srcs[j])[0];
            gv[2 * j + 1] = ((const float4*)srcs[j])[1];
        }
    }
    // stage-B kc=0 f32 weight fragments: issue now, complete under gather math
    const float* Wp = tB ? W1 : W0;
    const float* wp0 = Wp + (size_t)(nq * 32 + ln) * NFEAT + lg * 8;
    const float* wp1 = wp0 + 16 * NFEAT;
    float4 n00 = ((const float4*)wp0)[0], n01 = ((const float4*)wp0)[1];
    float4 n10 = ((const float4*)wp1)[0], n11 = ((const float4*)wp1)[1];

    // gather math: fold 1/||row|| into stored X, store swizzled bf16
    {
        char* xb = (char*)&Xbuf[0][0][0];
        #pragma unroll
        for (int j = 0; j < 4; ++j) {
            int p = w * 4 + j, t = p >> 4, m = p & 15;
            float4 a = gv[2 * j], b = gv[2 * j + 1];
            float ss = a.x*a.x + a.y*a.y + a.z*a.z + a.w*a.w
                     + b.x*b.x + b.y*b.y + b.z*b.z + b.w*b.w;
            #pragma unroll
            for (int d = 1; d < 64; d <<= 1) ss += __shfl_xor(ss, d);
            float scl = (ss > 0.f) ? (1.f / sqrtf(ss)) : 0.f;
            int soff = t * 16384 + m * 1024 + ((lane * 16) ^ ((m & 7) << 4));
            *(bf16x8*)(xb + soff) = pack8s(a, b, scl);
        }
    }
    __syncthreads();   // b1

    // ---- stage B: H[t] = relu(X'[t] @ W[t]^T); K=512, depth-1 prefetch, 4 chains ----
    {
        f32x4 a0e = zero4, a0o = zero4, a1e = zero4, a1o = zero4;
        const unsigned short* Xb = (const unsigned short*)((const char*)&Xbuf[0][0][0] + tB * 16384);
        #pragma unroll
        for (int kc = 0; kc < 16; ++kc) {
            bf16x8 cur0 = pack8(n00, n01);
            bf16x8 cur1 = pack8(n10, n11);
            if (kc < 15) {
                const float* q0 = wp0 + (kc + 1) * 32;
                const float* q1 = wp1 + (kc + 1) * 32;
                n00 = ((const float4*)q0)[0]; n01 = ((const float4*)q0)[1];
                n10 = ((const float4*)q1)[0]; n11 = ((const float4*)q1)[1];
            }
            bf16x8 a = ldsAx(Xb, ln, kc * 64 + lg * 16, 1024);
            if (kc & 1) { a0o = MFMA(a, cur0, a0o); a1o = MFMA(a, cur1, a1o); }
            else        { a0e = MFMA(a, cur0, a0e); a1e = MFMA(a, cur1, a1e); }
        }
        f32x4 acc0 = a0e + a0o, acc1 = a1e + a1o;
        unsigned short* Hb = &Hbuf[tB][0][0];
        #pragma unroll
        for (int rg = 0; rg < 4; ++rg) {
            int m = lg * 4 + rg;
            ldsW1(Hb, m, nq * 32 + ln,      f2bf(fmaxf(acc0[rg], 0.f)));
            ldsW1(Hb, m, nq * 32 + 16 + ln, f2bf(fmaxf(acc1[rg], 0.f)));
        }
    }
    // stage-C kc=0 fragments (independent of H): issue before the barrier
    const float* Gp = tB ? G2 : G1;
    const float* gp0 = Gp + (size_t)(nq * 32 + ln) * NHID + lg * 8;
    const float* gp1 = gp0 + 16 * NHID;
    float4 c00 = ((const float4*)gp0)[0], c01 = ((const float4*)gp0)[1];
    float4 c10 = ((const float4*)gp1)[0], c11 = ((const float4*)gp1)[1];
    __syncthreads();   // b2

    // ---- stage C: gate1/gate2 = H[t] @ G{1,2}^T; depth-1 prefetch ----
    {
        const unsigned short* Hs = &Hbuf[tB][0][0];
        f32x4 accC[2] = {zero4, zero4};
        #pragma unroll
        for (int kc = 0; kc < 4; ++kc) {
            bf16x8 cur0 = pack8(c00, c01);
            bf16x8 cur1 = pack8(c10, c11);
            if (kc < 3) {
                const float* q0 = gp0 + (kc + 1) * 32;
                const float* q1 = gp1 + (kc + 1) * 32;
                c00 = ((const float4*)q0)[0]; c01 = ((const float4*)q0)[1];
                c10 = ((const float4*)q1)[0]; c11 = ((const float4*)q1)[1];
            }
            bf16x8 a = ldsAx(Hs, ln, kc * 64 + lg * 16, 256);
            accC[0] = MFMA(a, cur0, accC[0]);
            accC[1] = MFMA(a, cur1, accC[1]);
        }
        unsigned short* Gd = G12 + tB * 2048;
        #pragma unroll
        for (int nt = 0; nt < 2; ++nt)
            #pragma unroll
            for (int rg = 0; rg < 4; ++rg) {
                int m = lg * 4 + rg;
                ldsW1(Gd, m, nq * 32 + nt * 16 + ln, f2bf(accC[nt][rg]));
            }
    }
    // stage-D kc=0 fragment (independent of G12): issue before the barrier
    const int nD = w * 16 + ln;
    const float* gtb = GT + (size_t)nD * (2 * NHID) + lg * 8;
    float4 d0 = ((const float4*)gtb)[0], d1 = ((const float4*)gtb)[1];
    __syncthreads();   // b3

    // ---- stage D: gate = sigmoid([g1,g2] @ GT^T); fix = (1-g)H0 + gH1; 2 chains ----
    {
        f32x4 accE_ = zero4, accO_ = zero4;
        #pragma unroll
        for (int kc = 0; kc < 8; ++kc) {
            bf16x8 cur = pack8(d0, d1);
            if (kc < 7) {
                const float* q = gtb + (kc + 1) * 32;
                d0 = ((const float4*)q)[0]; d1 = ((const float4*)q)[1];
            }
            const unsigned short* As = G12 + (kc >> 2) * 2048;
            bf16x8 a = ldsAx(As, ln, (kc & 3) * 64 + lg * 16, 256);
            if (kc & 1) accO_ = MFMA(a, cur, accO_); else accE_ = MFMA(a, cur, accE_);
        }
        f32x4 accD = accE_ + accO_;
        #pragma unroll
        for (int rg = 0; rg < 4; ++rg) {
            int m = lg * 4 + rg;
            float g  = 1.f / (1.f + __expf(-accD[rg]));
            float h0 = ldsR1(&Hbuf[0][0][0], m, nD);
            float h1 = ldsR1(&Hbuf[1][0][0], m, nD);
            ldsW1(FIX, m, nD, f2bf((1.f - g) * h0 + g * h1));
        }
    }
    __syncthreads();   // b4

    // ---- fix_inner row norms -> scl2 ----
    if (tid < 256) {
        int r = tid >> 4, sl = tid & 15;
        bf16x8 v = ldsAx(FIX, r, sl * 16, 256);
        float ss = 0.f;
        #pragma unroll
        for (int j = 0; j < 8; ++j) { float f = (float)v[j]; ss += f * f; }
        ss += __shfl_xor(ss, 1); ss += __shfl_xor(ss, 2);
        ss += __shfl_xor(ss, 4); ss += __shfl_xor(ss, 8);
        if (sl == 0) scl2[r] = (ss > 0.f) ? (1.f / sqrtf(ss)) : 0.f;
    }
    __syncthreads();   // b5

    // ---- stage E: logits = relu(scl2 * fix @ Wc^T); depth-1 prefetch, clamped rows ----
    if (w < 5) {
        const int cc = w * 16 + ln;
        const int ccl = (cc < NCLASS) ? cc : 0;          // clamped row for safe loads
        const bool live = (cc < NCLASS);
        const float* wcb = Wc + (size_t)ccl * NHID + lg * 8;
        float4 e0 = ((const float4*)wcb)[0], e1 = ((const float4*)wcb)[1];
        bf16x8 bfz;
        #pragma unroll
        for (int j = 0; j < 8; ++j) bfz[j] = (__bf16)0.f;
        f32x4 accE = zero4;
        #pragma unroll
        for (int kc = 0; kc < 4; ++kc) {
            bf16x8 cur = live ? pack8(e0, e1) : bfz;
            if (kc < 3) {
                const float* q = wcb + (kc + 1) * 32;
                e0 = ((const float4*)q)[0]; e1 = ((const float4*)q)[1];
            }
            bf16x8 a = ldsAx(FIX, ln, kc * 64 + lg * 16, 256);
            accE = MFMA(a, cur, accE);
        }
        #pragma unroll
        for (int rg = 0; rg < 4; ++rg) {
            int m = lg * 4 + rg;
            float v = fmaxf(accE[rg] * scl2[m], 0.f);
            LOG[m * 80 + cc] = (cc < NCLASS) ? v : -1e30f;
        }
    }
    __syncthreads();   // b6

    // ---- log_softmax + store ----
    {
        const int r = tid >> 5, l32 = tid & 31;
        float v0 = LOG[r * 80 + l32];
        float v1 = LOG[r * 80 + 32 + l32];
        float v2 = (l32 < 16) ? LOG[r * 80 + 64 + l32] : -1e30f;
        float mx = fmaxf(fmaxf(v0, v1), v2);
        #pragma unroll
        for (int d = 1; d < 32; d <<= 1) mx = fmaxf(mx, __shfl_xor(mx, d, 32));
        float se = __expf(v0 - mx) + __expf(v1 - mx) + ((l32 < 16) ? __expf(v2 - mx) : 0.f);
        #pragma unroll
        for (int d = 1; d < 32; d <<= 1) se += __shfl_xor(se, d, 32);
        float lz = mx + __logf(se);
        size_t orow = (size_t)bid * 16 + r;
        out[orow * NCLASS + l32] = v0 - lz;
        if (l32 + 32 < NCLASS) out[orow * NCLASS + 32 + l32] = v1 - lz;
        if (l32 + 64 < NCLASS) out[orow * NCLASS + 64 + l32] = v2 - lz;
    }
}

extern "C" void kernel_launch(void* const* d_in, const int* in_sizes, int n_in,
                              void* d_out, int out_size, void* d_ws, size_t ws_size,
                              hipStream_t stream)
{
    const float* x   = (const float*)d_in[0];
    const float* sf  = (const float*)d_in[1];
    const int*   idx = (const int*)d_in[2];
    const float* W0  = (const float*)d_in[3];
    const float* W1  = (const float*)d_in[4];
    const float* G1  = (const float*)d_in[5];
    const float* G2  = (const float*)d_in[6];
    const float* GT  = (const float*)d_in[7];
    const float* Wc  = (const float*)d_in[8];
    float* out = (float*)d_out;

    hyper_one<<<dim3(NTILE), dim3(512), 0, stream>>>(
        x, sf, idx, W0, W1, G1, G2, GT, Wc, out);
}

// Round 9
// 40.829 us; speedup vs baseline: 1.8711x; 1.8711x over previous
//
#include <hip/hip_runtime.h>
#include <math.h>

#define NFEAT  512
#define NHID   128
#define NCLASS 70
#define NIDX   10000
#define NTILE  625
#define HELEMS (2u * NIDX * NHID)          // 2,560,000 ushorts: H scratch
#define WIMG_ELEMS (2u * 128 * 512)        // 131,072 ushorts: W0/W1 LDS images
#define SMALL_ELEMS 74496u                 // G1,G2,GT,Wc row-major bf16
#define WS_NEED ((size_t)(HELEMS + WIMG_ELEMS + SMALL_ELEMS) * 2)

typedef float  f32x4  __attribute__((ext_vector_type(4)));
typedef __bf16 bf16x8 __attribute__((ext_vector_type(8)));

static __device__ __forceinline__ unsigned short f2bf(float f) {
    unsigned u = __builtin_bit_cast(unsigned, f);
    u += 0x7fffu + ((u >> 16) & 1u);
    return (unsigned short)(u >> 16);
}
static __device__ __forceinline__ float bf2f(unsigned short h) {
    unsigned u = ((unsigned)h) << 16;
    return __builtin_bit_cast(float, u);
}
static __device__ __forceinline__ bf16x8 pack8(float4 a, float4 b) {
    bf16x8 r;
    r[0] = (__bf16)a.x; r[1] = (__bf16)a.y; r[2] = (__bf16)a.z; r[3] = (__bf16)a.w;
    r[4] = (__bf16)b.x; r[5] = (__bf16)b.y; r[6] = (__bf16)b.z; r[7] = (__bf16)b.w;
    return r;
}
static __device__ __forceinline__ bf16x8 pack8s(float4 a, float4 b, float s) {
    bf16x8 r;
    r[0] = (__bf16)(a.x * s); r[1] = (__bf16)(a.y * s); r[2] = (__bf16)(a.z * s); r[3] = (__bf16)(a.w * s);
    r[4] = (__bf16)(b.x * s); r[5] = (__bf16)(b.y * s); r[6] = (__bf16)(b.z * s); r[7] = (__bf16)(b.w * s);
    return r;
}
static __device__ __forceinline__ f32x4 MFMA(bf16x8 a, bf16x8 b, f32x4 c) {
    return __builtin_amdgcn_mfma_f32_16x16x32_bf16(a, b, c, 0, 0, 0);
}
static __device__ __forceinline__ bf16x8 ldsAx(const unsigned short* base, int row, int colb, int rstride) {
    return *(const bf16x8*)((const char*)base + row * rstride + (colb ^ ((row & 7) << 4)));
}
static __device__ __forceinline__ void ldsW1(unsigned short* base, int row, int col, unsigned short v) {
    *(unsigned short*)((char*)base + row * 256 + ((col * 2) ^ ((row & 7) << 4))) = v;
}
static __device__ __forceinline__ float ldsR1(const unsigned short* base, int row, int col) {
    return bf2f(*(const unsigned short*)((const char*)base + row * 256 + ((col * 2) ^ ((row & 7) << 4))));
}

// ---- prep: W0/W1 -> pre-swizzled bf16 LDS images; G1/G2/GT/Wc -> row-major bf16 ----
__global__ void prep_weights(const float* __restrict__ W0, const float* __restrict__ W1,
                             const float* __restrict__ G1, const float* __restrict__ G2,
                             const float* __restrict__ GT, const float* __restrict__ Wc,
                             unsigned short* __restrict__ wsWimg,
                             unsigned short* __restrict__ wsSmall) {
    int i = blockIdx.x * 256 + threadIdx.x;
    if (i < 16384) {
        // W images: task = (t, row n, col-group k8 of 8 cols)
        int t = i >> 13;
        int r = i & 8191;
        int n = r >> 6, k8 = r & 63;
        const float* src = (t ? W1 : W0) + (size_t)n * NFEAT + k8 * 8;
        float4 a = ((const float4*)src)[0], b = ((const float4*)src)[1];
        char* dst = (char*)wsWimg + t * 131072 + n * 1024 + ((k8 * 16) ^ ((n & 7) << 4));
        *(bf16x8*)dst = pack8(a, b);
    } else {
        int i4 = i - 16384;
        if (i4 >= 18624) return;
        const float* src; int base4, dstb;
        if      (i4 < 4096)  { src = G1; base4 = 0;     dstb = 0; }
        else if (i4 < 8192)  { src = G2; base4 = 4096;  dstb = 16384; }
        else if (i4 < 16384) { src = GT; base4 = 8192;  dstb = 32768; }
        else                 { src = Wc; base4 = 16384; dstb = 65536; }
        float4 v = ((const float4*)src)[i4 - base4];
        ushort4 o;
        o.x = f2bf(v.x); o.y = f2bf(v.y); o.z = f2bf(v.z); o.w = f2bf(v.w);
        *(ushort4*)(wsSmall + dstb + (size_t)(i4 - base4) * 4) = o;
    }
}

// ---- stage B, weights-stationary: 250 blocks (2 tensors x 125), 5 tiles each ----
// W image (128 KB) resident in LDS; inner loop is pure LDS->MFMA.
__global__ __launch_bounds__(512) void stageB_ws(
    const float* __restrict__ x, const float* __restrict__ sf,
    const int* __restrict__ idx,
    const unsigned short* __restrict__ wsWimg,
    unsigned short* __restrict__ wsH)
{
    __shared__ __align__(16) unsigned short Wl[65536];  // 128 KB swizzled W image
    __shared__ __align__(16) unsigned short Xl[8192];   // 16 KB swizzled X tile
    __shared__ __align__(16) unsigned short Hl[2048];   // 4 KB swizzled H tile

    const int tid  = threadIdx.x;
    const int w    = tid >> 6;          // wave 0..7
    const int lane = tid & 63;
    const int ln   = lane & 15, lg = lane >> 4;
    const int bid  = blockIdx.x;
    const int t    = bid / 125, tb = bid % 125;
    const int tile0 = tb * 5;
    const float* XS = t ? sf : x;
    const f32x4 zero4 = {0.f, 0.f, 0.f, 0.f};

    // gather volley for tile 0 (wave w owns rows w and w+8) — issue before W copy
    float4 ga0, ga1, gb0, gb1;
    {
        int r0 = idx[tile0 * 16 + w];
        int r1 = idx[tile0 * 16 + w + 8];
        const float4* p0 = (const float4*)(XS + (size_t)r0 * NFEAT + lane * 8);
        const float4* p1 = (const float4*)(XS + (size_t)r1 * NFEAT + lane * 8);
        ga0 = p0[0]; ga1 = p0[1];
        gb0 = p1[0]; gb1 = p1[1];
    }
    // W image -> LDS: linear 128 KB copy (L2-hot after first blocks)
    {
        const uint4* src = (const uint4*)((const char*)wsWimg + (size_t)t * 131072);
        uint4* dst = (uint4*)Wl;
        #pragma unroll
        for (int i = 0; i < 16; ++i) dst[tid + i * 512] = src[tid + i * 512];
    }
    // norm + store X tile 0 (scale folded into stored bf16)
    auto putX = [&](int m, float4 a, float4 b) {
        float ss = a.x*a.x + a.y*a.y + a.z*a.z + a.w*a.w
                 + b.x*b.x + b.y*b.y + b.z*b.z + b.w*b.w;
        #pragma unroll
        for (int d = 1; d < 64; d <<= 1) ss += __shfl_xor(ss, d);
        float scl = (ss > 0.f) ? (1.f / sqrtf(ss)) : 0.f;
        *(bf16x8*)((char*)Xl + m * 1024 + ((lane * 16) ^ ((m & 7) << 4))) = pack8s(a, b, scl);
    };
    putX(w,     ga0, ga1);
    putX(w + 8, gb0, gb1);
    __syncthreads();

    for (int it = 0; it < 5; ++it) {
        // prefetch next tile's gather volley (hides HBM latency under MFMA)
        float4 na0, na1, nb0, nb1;
        if (it < 4) {
            int tile = tile0 + it + 1;
            int r0 = idx[tile * 16 + w];
            int r1 = idx[tile * 16 + w + 8];
            const float4* p0 = (const float4*)(XS + (size_t)r0 * NFEAT + lane * 8);
            const float4* p1 = (const float4*)(XS + (size_t)r1 * NFEAT + lane * 8);
            na0 = p0[0]; na1 = p0[1];
            nb0 = p1[0]; nb1 = p1[1];
        }
        // compute: wave w -> output cols w*16..w*16+15; both operands from LDS
        f32x4 accE = zero4, accO = zero4;
        #pragma unroll
        for (int kc = 0; kc < 16; ++kc) {
            bf16x8 a = ldsAx(Xl, ln,          kc * 64 + lg * 16, 1024);
            bf16x8 b = ldsAx(Wl, w * 16 + ln, kc * 64 + lg * 16, 1024);
            if (kc & 1) accO = MFMA(a, b, accO); else accE = MFMA(a, b, accE);
        }
        f32x4 acc = accE + accO;
        #pragma unroll
        for (int rg = 0; rg < 4; ++rg)
            ldsW1(Hl, lg * 4 + rg, w * 16 + ln, f2bf(fmaxf(acc[rg], 0.f)));
        __syncthreads();   // X reads + Hl writes complete

        // H tile -> ws (coalesced 4 KB), overlapped with next-X store
        if (tid < 256) {
            int tile = tile0 + it;
            ((uint4*)(wsH + ((size_t)t * NIDX + (size_t)tile * 16) * NHID))[tid]
                = ((const uint4*)Hl)[tid];
        }
        if (it < 4) {
            putX(w,     na0, na1);
            putX(w + 8, nb0, nb1);
        }
        __syncthreads();   // Xl ready, Hl copy drained
    }
}

// ---- tail: stages C/D/E + softmax (r7 structure, proven) ----
__global__ __launch_bounds__(512) void tailCDE(
    const unsigned short* __restrict__ wsSmall,
    const unsigned short* __restrict__ wsH,
    float* __restrict__ out)
{
    __shared__ __align__(16) unsigned short Hbuf[2][16][NHID]; // 8 KB (swizzle baked)
    __shared__ __align__(16) unsigned short Scr[8704];         // G12 | FIX | LOG
    __shared__ float scl2[16];

    unsigned short* G12 = Scr;
    unsigned short* FIX = Scr + 4096;
    float*          LOG = (float*)(Scr + 6144);

    const unsigned short* G1p = wsSmall;
    const unsigned short* G2p = wsSmall + 16384;
    const unsigned short* GTp = wsSmall + 32768;
    const unsigned short* Wcp = wsSmall + 65536;

    const int tid  = threadIdx.x;
    const int bid  = blockIdx.x;
    const int w    = tid >> 6;
    const int lane = tid & 63;
    const int ln   = lane & 15, lg = lane >> 4;
    const int tB = w >> 2, nq = w & 3;
    const f32x4 zero4 = {0.f, 0.f, 0.f, 0.f};

    {
        int tt = tid >> 8, r = tid & 255;
        uint4 v = *(const uint4*)((const char*)wsH
                    + ((size_t)tt * NIDX + (size_t)bid * 16) * 256 + r * 16);
        ((uint4*)&Hbuf[0][0][0])[tid] = v;
    }
    bf16x8 cf[8];
    {
        const unsigned short* Gp = tB ? G2p : G1p;
        #pragma unroll
        for (int kc = 0; kc < 4; ++kc)
            #pragma unroll
            for (int nt = 0; nt < 2; ++nt)
                cf[kc * 2 + nt] = *(const bf16x8*)(Gp + (size_t)(nq * 32 + nt * 16 + ln) * NHID + kc * 32 + lg * 8);
    }
    __syncthreads();

    {
        const unsigned short* Hs = &Hbuf[tB][0][0];
        f32x4 accC[2] = {zero4, zero4};
        #pragma unroll
        for (int kc = 0; kc < 4; ++kc) {
            bf16x8 a = ldsAx(Hs, ln, kc * 64 + lg * 16, 256);
            accC[0] = MFMA(a, cf[kc * 2],     accC[0]);
            accC[1] = MFMA(a, cf[kc * 2 + 1], accC[1]);
        }
        unsigned short* Gd = G12 + tB * 2048;
        #pragma unroll
        for (int nt = 0; nt < 2; ++nt)
            #pragma unroll
            for (int rg = 0; rg < 4; ++rg) {
                int m = lg * 4 + rg;
                ldsW1(Gd, m, nq * 32 + nt * 16 + ln, f2bf(accC[nt][rg]));
            }
    }
    __syncthreads();

    {
        f32x4 accE_ = zero4, accO_ = zero4;
        const int n = w * 16 + ln;
        #pragma unroll
        for (int kc = 0; kc < 8; ++kc) {
            const unsigned short* As = G12 + (kc >> 2) * 2048;
            bf16x8 a = ldsAx(As, ln, (kc & 3) * 64 + lg * 16, 256);
            bf16x8 b = *(const bf16x8*)(GTp + (size_t)n * (2 * NHID) + kc * 32 + lg * 8);
            if (kc & 1) accO_ = MFMA(a, b, accO_); else accE_ = MFMA(a, b, accE_);
        }
        f32x4 accD = accE_ + accO_;
        #pragma unroll
        for (int rg = 0; rg < 4; ++rg) {
            int m = lg * 4 + rg;
            float g  = 1.f / (1.f + __expf(-accD[rg]));
            float h0 = ldsR1(&Hbuf[0][0][0], m, n);
            float h1 = ldsR1(&Hbuf[1][0][0], m, n);
            ldsW1(FIX, m, n, f2bf((1.f - g) * h0 + g * h1));
        }
    }
    __syncthreads();

    if (tid < 256) {
        int r = tid >> 4, sl = tid & 15;
        bf16x8 v = ldsAx(FIX, r, sl * 16, 256);
        float ss = 0.f;
        #pragma unroll
        for (int j = 0; j < 8; ++j) { float f = (float)v[j]; ss += f * f; }
        ss += __shfl_xor(ss, 1); ss += __shfl_xor(ss, 2);
        ss += __shfl_xor(ss, 4); ss += __shfl_xor(ss, 8);
        if (sl == 0) scl2[r] = (ss > 0.f) ? (1.f / sqrtf(ss)) : 0.f;
    }
    __syncthreads();

    if (w < 5) {
        const int cc = w * 16 + ln;
        bf16x8 bfz;
        #pragma unroll
        for (int j = 0; j < 8; ++j) bfz[j] = (__bf16)0.f;
        f32x4 accE = zero4;
        #pragma unroll
        for (int kc = 0; kc < 4; ++kc) {
            bf16x8 a = ldsAx(FIX, ln, kc * 64 + lg * 16, 256);
            bf16x8 b = (cc < NCLASS) ? *(const bf16x8*)(Wcp + (size_t)cc * NHID + kc * 32 + lg * 8) : bfz;
            accE = MFMA(a, b, accE);
        }
        #pragma unroll
        for (int rg = 0; rg < 4; ++rg) {
            int m = lg * 4 + rg;
            float v = fmaxf(accE[rg] * scl2[m], 0.f);
            LOG[m * 80 + cc] = (cc < NCLASS) ? v : -1e30f;
        }
    }
    __syncthreads();

    {
        const int r = tid >> 5, l32 = tid & 31;
        float v0 = LOG[r * 80 + l32];
        float v1 = LOG[r * 80 + 32 + l32];
        float v2 = (l32 < 16) ? LOG[r * 80 + 64 + l32] : -1e30f;
        float mx = fmaxf(fmaxf(v0, v1), v2);
        #pragma unroll
        for (int d = 1; d < 32; d <<= 1) mx = fmaxf(mx, __shfl_xor(mx, d, 32));
        float se = __expf(v0 - mx) + __expf(v1 - mx) + ((l32 < 16) ? __expf(v2 - mx) : 0.f);
        #pragma unroll
        for (int d = 1; d < 32; d <<= 1) se += __shfl_xor(se, d, 32);
        float lz = mx + __logf(se);
        size_t orow = (size_t)bid * 16 + r;
        out[orow * NCLASS + l32] = v0 - lz;
        if (l32 + 32 < NCLASS) out[orow * NCLASS + 32 + l32] = v1 - lz;
        if (l32 + 64 < NCLASS) out[orow * NCLASS + 64 + l32] = v2 - lz;
    }
}

// ---- fallback (ws too small): round-6 fused kernel, f32 weights inline ----
static __device__ __forceinline__ bf16x8 bfragF(const float* p, size_t off) {
    const float4* q = (const float4*)(p + off);
    return pack8(q[0], q[1]);
}
__global__ __launch_bounds__(512) void hyper_fb(
    const float* __restrict__ x, const float* __restrict__ sf,
    const int* __restrict__ idx,
    const float* __restrict__ W0, const float* __restrict__ W1,
    const float* __restrict__ G1, const float* __restrict__ G2,
    const float* __restrict__ GT, const float* __restrict__ Wc,
    float* __restrict__ out)
{
    __shared__ __align__(16) unsigned short Xbuf[2][16][NFEAT];
    __shared__ __align__(16) unsigned short Hbuf[2][16][NHID];
    __shared__ float scl2[16];
    unsigned short* G12 = &Xbuf[0][0][0];
    unsigned short* FIX = &Xbuf[0][0][0] + 4096;
    float*          LOG = (float*)(&Xbuf[0][0][0] + 6144);

    const int tid = threadIdx.x, bid = blockIdx.x;
    const int w = tid >> 6, lane = tid & 63;
    const int ln = lane & 15, lg = lane >> 4;
    const int tB = w >> 2, nq = w & 3;
    const f32x4 zero4 = {0.f, 0.f, 0.f, 0.f};

    {
        char* xb = (char*)&Xbuf[0][0][0];
        #pragma unroll
        for (int j = 0; j < 4; ++j) {
            int p = w * 4 + j, t = p >> 4, m = p & 15;
            int ri = idx[bid * 16 + m];
            const float4* q = (const float4*)((t ? sf : x) + (size_t)ri * NFEAT + lane * 8);
            float4 a = q[0], b = q[1];
            float ss = a.x*a.x + a.y*a.y + a.z*a.z + a.w*a.w
                     + b.x*b.x + b.y*b.y + b.z*b.z + b.w*b.w;
            #pragma unroll
            for (int d = 1; d < 64; d <<= 1) ss += __shfl_xor(ss, d);
            float scl = (ss > 0.f) ? (1.f / sqrtf(ss)) : 0.f;
            int soff = t * 16384 + m * 1024 + ((lane * 16) ^ ((m & 7) << 4));
            *(bf16x8*)(xb + soff) = pack8s(a, b, scl);
        }
    }
    __syncthreads();
    {
        const float* Wp = tB ? W1 : W0;
        f32x4 acc0 = zero4, acc1 = zero4;
        const unsigned short* Xb = (const unsigned short*)((const char*)&Xbuf[0][0][0] + tB * 16384);
        #pragma unroll
        for (int kc = 0; kc < 16; ++kc) {
            bf16x8 a = ldsAx(Xb, ln, kc * 64 + lg * 16, 1024);
            acc0 = MFMA(a, bfragF(Wp, (size_t)(nq * 32 + ln) * NFEAT + kc * 32 + lg * 8), acc0);
            acc1 = MFMA(a, bfragF(Wp, (size_t)(nq * 32 + 16 + ln) * NFEAT + kc * 32 + lg * 8), acc1);
        }
        unsigned short* Hb = &Hbuf[tB][0][0];
        #pragma unroll
        for (int rg = 0; rg < 4; ++rg) {
            int m = lg * 4 + rg;
            ldsW1(Hb, m, nq * 32 + ln,      f2bf(fmaxf(acc0[rg], 0.f)));
            ldsW1(Hb, m, nq * 32 + 16 + ln, f2bf(fmaxf(acc1[rg], 0.f)));
        }
    }
    __syncthreads();
    {
        const float* Gp = tB ? G2 : G1;
        const unsigned short* Hs = &Hbuf[tB][0][0];
        f32x4 accC[2] = {zero4, zero4};
        #pragma unroll
        for (int kc = 0; kc < 4; ++kc) {
            bf16x8 a = ldsAx(Hs, ln, kc * 64 + lg * 16, 256);
            accC[0] = MFMA(a, bfragF(Gp, (size_t)(nq * 32 + ln) * NHID + kc * 32 + lg * 8), accC[0]);
            accC[1] = MFMA(a, bfragF(Gp, (size_t)(nq * 32 + 16 + ln) * NHID + kc * 32 + lg * 8), accC[1]);
        }
        unsigned short* Gd = G12 + tB * 2048;
        #pragma unroll
        for (int nt = 0; nt < 2; ++nt)
            #pragma unroll
            for (int rg = 0; rg < 4; ++rg) {
                int m = lg * 4 + rg;
                ldsW1(Gd, m, nq * 32 + nt * 16 + ln, f2bf(accC[nt][rg]));
            }
    }
    __syncthreads();
    {
        f32x4 accD = zero4;
        const int n = w * 16 + ln;
        #pragma unroll
        for (int kc = 0; kc < 8; ++kc) {
            const unsigned short* As = G12 + (kc >> 2) * 2048;
            bf16x8 a = ldsAx(As, ln, (kc & 3) * 64 + lg * 16, 256);
            accD = MFMA(a, bfragF(GT, (size_t)n * (2 * NHID) + kc * 32 + lg * 8), accD);
        }
        #pragma unroll
        for (int rg = 0; rg < 4; ++rg) {
            int m = lg * 4 + rg;
            float g  = 1.f / (1.f + __expf(-accD[rg]));
            float h0 = ldsR1(&Hbuf[0][0][0], m, n);
            float h1 = ldsR1(&Hbuf[1][0][0], m, n);
            ldsW1(FIX, m, n, f2bf((1.f - g) * h0 + g * h1));
        }
    }
    __syncthreads();
    if (tid < 256) {
        int r = tid >> 4, sl = tid & 15;
        bf16x8 v = ldsAx(FIX, r, sl * 16, 256);
        float ss = 0.f;
        #pragma unroll
        for (int j = 0; j < 8; ++j) { float f = (float)v[j]; ss += f * f; }
        ss += __shfl_xor(ss, 1); ss += __shfl_xor(ss, 2);
        ss += __shfl_xor(ss, 4); ss += __shfl_xor(ss, 8);
        if (sl == 0) scl2[r] = (ss > 0.f) ? (1.f / sqrtf(ss)) : 0.f;
    }
    __syncthreads();
    if (w < 5) {
        const int cc = w * 16 + ln;
        bf16x8 bfz;
        #pragma unroll
        for (int j = 0; j < 8; ++j) bfz[j] = (__bf16)0.f;
        f32x4 accE = zero4;
        #pragma unroll
        for (int kc = 0; kc < 4; ++kc) {
            bf16x8 a = ldsAx(FIX, ln, kc * 64 + lg * 16, 256);
            bf16x8 b = (cc < NCLASS) ? bfragF(Wc, (size_t)cc * NHID + kc * 32 + lg * 8) : bfz;
            accE = MFMA(a, b, accE);
        }
        #pragma unroll
        for (int rg = 0; rg < 4; ++rg) {
            int m = lg * 4 + rg;
            float v = fmaxf(accE[rg] * scl2[m], 0.f);
            LOG[m * 80 + cc] = (cc < NCLASS) ? v : -1e30f;
        }
    }
    __syncthreads();
    {
        const int r = tid >> 5, l32 = tid & 31;
        float v0 = LOG[r * 80 + l32];
        float v1 = LOG[r * 80 + 32 + l32];
        float v2 = (l32 < 16) ? LOG[r * 80 + 64 + l32] : -1e30f;
        float mx = fmaxf(fmaxf(v0, v1), v2);
        #pragma unroll
        for (int d = 1; d < 32; d <<= 1) mx = fmaxf(mx, __shfl_xor(mx, d, 32));
        float se = __expf(v0 - mx) + __expf(v1 - mx) + ((l32 < 16) ? __expf(v2 - mx) : 0.f);
        #pragma unroll
        for (int d = 1; d < 32; d <<= 1) se += __shfl_xor(se, d, 32);
        float lz = mx + __logf(se);
        size_t orow = (size_t)bid * 16 + r;
        out[orow * NCLASS + l32] = v0 - lz;
        if (l32 + 32 < NCLASS) out[orow * NCLASS + 32 + l32] = v1 - lz;
        if (l32 + 64 < NCLASS) out[orow * NCLASS + 64 + l32] = v2 - lz;
    }
}

extern "C" void kernel_launch(void* const* d_in, const int* in_sizes, int n_in,
                              void* d_out, int out_size, void* d_ws, size_t ws_size,
                              hipStream_t stream)
{
    const float* x   = (const float*)d_in[0];
    const float* sf  = (const float*)d_in[1];
    const int*   idx = (const int*)d_in[2];
    const float* W0  = (const float*)d_in[3];
    const float* W1  = (const float*)d_in[4];
    const float* G1  = (const float*)d_in[5];
    const float* G2  = (const float*)d_in[6];
    const float* GT  = (const float*)d_in[7];
    const float* Wc  = (const float*)d_in[8];
    float* out = (float*)d_out;

    if (ws_size >= WS_NEED) {
        unsigned short* wsH     = (unsigned short*)d_ws;
        unsigned short* wsWimg  = wsH + HELEMS;
        unsigned short* wsSmall = wsWimg + WIMG_ELEMS;
        prep_weights<<<dim3(137), dim3(256), 0, stream>>>(W0, W1, G1, G2, GT, Wc, wsWimg, wsSmall);
        stageB_ws<<<dim3(250), dim3(512), 0, stream>>>(x, sf, idx, wsWimg, wsH);
        tailCDE<<<dim3(NTILE), dim3(512), 0, stream>>>(wsSmall, wsH, out);
    } else {
        hyper_fb<<<dim3(NTILE), dim3(512), 0, stream>>>(
            x, sf, idx, W0, W1, G1, G2, GT, Wc, out);
    }
}